// Round 13
// baseline (211.591 us; speedup 1.0000x reference)
//
#include <hip/hip_runtime.h>

// RRF2d via MFMA: per p, C[32b x 32o] += A[32 x K] * B[K x 32o], K = 288
// padded to 512 (16 slots per input channel). bf16 inputs, fp32 accum.
//
// Invariance trick: A and B LDS slabs are both stored with position
// q = g*8+j enumerating MY k-order; since MFMA contracts A[m][k]B[k][n]
// with the SAME (lane-group, elem)->k map for both operands, any k-relabel
// applied to both is a no-op. Only assumed: row/col = lane&15, group =
// lane>>4 (consistent with m89-verified C/D layout + verified gemm_bt).
//
// Block: 512 thr (8 waves), owns p-tile 32 (half image row), o-tile 32,
// all 32 b. Grid (128, 2) = 256 blocks = 1/CU. LDS: A 64KB + B 64KB,
// single-buffered; serial per-c-pair rhythm: compute -> barrier ->
// stage(next) -> barrier. Epilogue transposes acc via LDS for coalesced
// float4 stores. XOR(pl&7) swizzle bounds LDS conflicts to <=4-way.

#define C_IN   32
#define HH     64
#define WW     64
#define C_OUTV 64
#define LL     4096
#define KLT    288

typedef __attribute__((ext_vector_type(8))) short short8;
typedef __attribute__((ext_vector_type(4))) float f32x4;

__device__ __forceinline__ short bf16_of(float f) {
    unsigned u = __builtin_bit_cast(unsigned, f);
    unsigned r = (u + 0x7FFFu + ((u >> 16) & 1u)) >> 16;   // RNE
    return (short)r;
}

__global__ __launch_bounds__(512, 2)
void rrf2d_mfma(const float* __restrict__ x, const float* __restrict__ wgt,
                const float* __restrict__ bias, float* __restrict__ out) {
    __shared__ char lds_raw[131072];
    short* Asl = (short*)lds_raw;              // [pl][g][mslot^xor][j]  64KB
    short* Bsl = (short*)(lds_raw + 65536);    // [pl][g][oslot^xor][j]  64KB

    const int lane = threadIdx.x;                                  // 0..63
    const int wyu  = __builtin_amdgcn_readfirstlane(threadIdx.y);  // 0..7
    const int tid  = threadIdx.y * 64 + lane;                      // 0..511

    const int bx = blockIdx.x;            // 0..127
    const int h0 = bx >> 1;
    const int w0 = (bx & 1) * 32;
    const int p0 = h0 * WW + w0;
    const int og = blockIdx.y * 32;

    // staging thread map
    const int pls = tid & 31;             // p within tile
    const int u   = tid >> 5;             // 0..15
    const int xsw = pls & 7;              // xor swizzle key

    // x tap geometry (clamped addrs + validity masks)
    int rc[3]; float rv[3];
    #pragma unroll
    for (int dh = 0; dh < 3; ++dh) {
        const int r = h0 + dh - 1;
        rv[dh] = (r >= 0 && r < HH) ? 1.f : 0.f;
        rc[dh] = (r < 0 ? 0 : (r > HH - 1 ? HH - 1 : r)) * WW;
    }
    int cc[3]; float cv[3];
    #pragma unroll
    for (int dw = 0; dw < 3; ++dw) {
        const int c_ = w0 + pls + dw - 1;
        cv[dw] = (c_ >= 0 && c_ < WW) ? 1.f : 0.f;
        cc[dw] = c_ < 0 ? 0 : (c_ > WW - 1 ? WW - 1 : c_);
    }

    // zero B slab once (k-pad slots j=1..7 of odd-g rows persist as 0)
    #pragma unroll
    for (int z = 0; z < 8; ++z) {
        short8 zz = {0, 0, 0, 0, 0, 0, 0, 0};
        *(short8*)(Bsl + ((size_t)z * 512 + tid) * 8) = zz;
    }
    __syncthreads();   // memset visible before stage(0) writes

    f32x4 acc[4][2][2];
    #pragma unroll
    for (int pz = 0; pz < 4; ++pz)
        #pragma unroll
        for (int mh = 0; mh < 2; ++mh)
            #pragma unroll
            for (int nh = 0; nh < 2; ++nh)
                #pragma unroll
                for (int r = 0; r < 4; ++r) acc[pz][mh][nh][r] = 0.f;

    // ---- stage c-pair cp into the slabs (loads + cvt + ds_write) ----
    auto STAGE = [&](int cp) {
        #pragma unroll
        for (int c2 = 0; c2 < 2; ++c2) {
            const int c = 2 * cp + c2;
            // B: weight pairs (taps 0..7 as 4 b32 writes) + single (tap 8)
            #pragma unroll
            for (int e = 0; e < 8; ++e) {
                const int o  = u + 16 * (e & 1);
                const int tp = e >> 1;
                const float* g0 = wgt + ((size_t)(og + o) * KLT + c * 9 + 2 * tp) * LL
                                + p0 + pls;
                const float v0 = g0[0];
                const float v1 = g0[LL];
                const unsigned pk = (unsigned)(unsigned short)bf16_of(v0)
                                  | ((unsigned)(unsigned short)bf16_of(v1) << 16);
                const int slot = ((pls * 4 + c2 * 2) * 32) + (o ^ xsw);
                *(unsigned*)((char*)Bsl + (size_t)slot * 16 + tp * 4) = pk;
            }
            #pragma unroll
            for (int e = 0; e < 2; ++e) {
                const int o = u + 16 * e;
                const float v = *(wgt + ((size_t)(og + o) * KLT + c * 9 + 8) * LL
                                  + p0 + pls);
                const int slot = ((pls * 4 + c2 * 2 + 1) * 32) + (o ^ xsw);
                Bsl[(size_t)slot * 8] = bf16_of(v);
            }
            // A: patches materialization, 2 b's per thread
            #pragma unroll
            for (int bi = 0; bi < 2; ++bi) {
                const int b = u + 16 * bi;
                const float* xb = x + ((size_t)b * C_IN + c) * (HH * WW);
                float t[9];
                #pragma unroll
                for (int dh = 0; dh < 3; ++dh)
                    #pragma unroll
                    for (int dw = 0; dw < 3; ++dw)
                        t[dh * 3 + dw] = xb[rc[dh] + cc[dw]] * (rv[dh] * cv[dw]);
                short8 s0, s1;
                #pragma unroll
                for (int j = 0; j < 8; ++j) s0[j] = bf16_of(t[j]);
                s1[0] = bf16_of(t[8]);
                #pragma unroll
                for (int j = 1; j < 8; ++j) s1[j] = 0;
                const int slot = ((pls * 4 + c2 * 2) * 32) + (b ^ xsw);
                short* dst = Asl + (size_t)slot * 8;
                *(short8*)dst = s0;
                *(short8*)(dst + 256) = s1;        // g+1: +32 slots * 8 shorts
            }
        }
    };

    const int lm = lane & 15;
    const int lg = lane >> 4;

    STAGE(0);
    __syncthreads();

    for (int cp = 0; cp < 16; ++cp) {
        // compute: 4 p's x (2 mh x 2 nh) MFMA tiles per wave
        #pragma unroll
        for (int pz = 0; pz < 4; ++pz) {
            const int pl = wyu * 4 + pz;
            const int px = pl & 7;
            const int rowbase = (pl * 4 + lg) * 32;
            const short8 af0 = *(const short8*)(Asl + (size_t)(rowbase + (lm ^ px)) * 8);
            const short8 af1 = *(const short8*)(Asl + (size_t)(rowbase + ((16 + lm) ^ px)) * 8);
            const short8 bf0 = *(const short8*)(Bsl + (size_t)(rowbase + (lm ^ px)) * 8);
            const short8 bf1 = *(const short8*)(Bsl + (size_t)(rowbase + ((16 + lm) ^ px)) * 8);
            acc[pz][0][0] = __builtin_amdgcn_mfma_f32_16x16x32_bf16(af0, bf0, acc[pz][0][0], 0, 0, 0);
            acc[pz][0][1] = __builtin_amdgcn_mfma_f32_16x16x32_bf16(af0, bf1, acc[pz][0][1], 0, 0, 0);
            acc[pz][1][0] = __builtin_amdgcn_mfma_f32_16x16x32_bf16(af1, bf0, acc[pz][1][0], 0, 0, 0);
            acc[pz][1][1] = __builtin_amdgcn_mfma_f32_16x16x32_bf16(af1, bf1, acc[pz][1][1], 0, 0, 0);
        }
        __syncthreads();               // all frag reads of this cp done
        if (cp < 15) {
            STAGE(cp + 1);             // slabs rewritten in place
            __syncthreads();
        }
    }

    // ---- epilogue: transpose acc via (wave-private) LDS, coalesced stores
    float* scr = (float*)lds_raw + (size_t)wyu * 4096;   // 16KB per wave
    #pragma unroll
    for (int pz = 0; pz < 4; ++pz)
        #pragma unroll
        for (int mh = 0; mh < 2; ++mh)
            #pragma unroll
            for (int nh = 0; nh < 2; ++nh)
                #pragma unroll
                for (int r = 0; r < 4; ++r) {
                    const int b = mh * 16 + lg * 4 + r;
                    const int o = nh * 16 + lm;
                    scr[(size_t)(b * 32 + o) * 4 + pz] = acc[pz][mh][nh][r];
                }
    // wave-private region: no barrier needed (compiler inserts lgkmcnt)
    #pragma unroll
    for (int it = 0; it < 16; ++it) {
        const int idx = it * 64 + lane;
        const int b = idx >> 5;
        const int o = idx & 31;
        f32x4 v = *(const f32x4*)(scr + (size_t)(b * 32 + o) * 4);
        const f32x4 bb = *(const f32x4*)(bias + (size_t)(og + o) * LL + p0 + wyu * 4);
        v += bb;
        *(f32x4*)(out + ((size_t)b * C_OUTV + og + o) * LL + p0 + wyu * 4) = v;
    }
}

extern "C" void kernel_launch(void* const* d_in, const int* in_sizes, int n_in,
                              void* d_out, int out_size, void* d_ws, size_t ws_size,
                              hipStream_t stream) {
    const float* x    = (const float*)d_in[0];
    const float* wgt  = (const float*)d_in[1];
    const float* bias = (const float*)d_in[2];
    float* out        = (float*)d_out;

    dim3 block(64, 8);        // 8 waves
    dim3 grid(128, 2);        // 128 p-tiles x 2 o-halves = 256 = 1/CU

    hipLaunchKernelGGL(rrf2d_mfma, grid, block, 0, stream, x, wgt, bias, out);
}